// Round 20
// baseline (336.692 us; speedup 1.0000x reference)
//
#include <hip/hip_runtime.h>
#include <hip/hip_bf16.h>
#include <hip/hip_fp16.h>

#define Hdim 256
#define Tdim 256
#define Bdim 512
#define TT   64
#define NTILE (Tdim / TT)   // 4
#define NTHR 256
#define NCP  32             // cp2 prep blocks (16 batches each)

typedef __attribute__((ext_vector_type(8))) short s16x8;
typedef __attribute__((ext_vector_type(8))) _Float16 f16x8;
typedef __attribute__((ext_vector_type(2))) _Float16 f16x2;
typedef __attribute__((ext_vector_type(4))) float f32x4;
typedef unsigned short u16;
typedef unsigned int u32;

__device__ __forceinline__ u32 cvt_pk_f16(float lo, float hi) {
    auto v = __builtin_amdgcn_cvt_pkrtz(lo, hi);
    return __builtin_bit_cast(u32, v);
}
__device__ __forceinline__ u16 f2h_rne(float x) {
    _Float16 h = (_Float16)x;
    return __builtin_bit_cast(u16, h);
}
__device__ __forceinline__ f32x4 mfma16h(s16x8 a, s16x8 b, f32x4 c) {
    return __builtin_amdgcn_mfma_f32_16x16x32_f16(
        __builtin_bit_cast(f16x8, a), __builtin_bit_cast(f16x8, b), c, 0, 0, 0);
}
__device__ __forceinline__ float fast_tanh(float z) {
    float e = __expf(2.0f * z);
    return 1.0f - 2.0f * __builtin_amdgcn_rcpf(e + 1.0f);
}
__device__ __forceinline__ s16x8 bfrag_f32(const float* __restrict__ wp) {
    float4 x0 = *(const float4*)(wp + 0);
    float4 x1 = *(const float4*)(wp + 4);
    uint4 uu = make_uint4(cvt_pk_f16(x0.x, x0.y), cvt_pk_f16(x0.z, x0.w),
                          cvt_pk_f16(x1.x, x1.y), cvt_pk_f16(x1.z, x1.w));
    return __builtin_bit_cast(s16x8, uu);
}

// ---- prep: [0,256) Wcomb fold; [256,256+NCP) cp2 MFMA, 16 batches per block ----
// (r15's cp2 used 8 blocks = 8 CUs busy -> prep critical path; now 32-way.)
// Blocks 0,1 also zero the combine counters (re-zeroed every launch -> replay-safe).
__global__ __launch_bounds__(256) void prep_kernel(
        const float* __restrict__ W_Ih, const float* __restrict__ W_oI,
        const float* __restrict__ W_I1T, const float* __restrict__ W_I1L,
        const float* __restrict__ h_tilde, const float* __restrict__ c_t,
        const float* __restrict__ W_I, const float* __restrict__ b_I,
        const float* __restrict__ b_oI,
        u16* __restrict__ Wph, float* __restrict__ wT2, float* __restrict__ wL2,
        float* __restrict__ cp2, int* __restrict__ cnt) {
    __shared__ char smem[24576];           // fold: sWo 1KB | cp2: hh 16KB + cpl 8KB
    __shared__ float redT[4], redL[4];
    const int tid = threadIdx.x;
    const int w = tid >> 6, lane = tid & 63;
    const int c = lane & 15, g = lane >> 4;

    if (blockIdx.x < 2) cnt[blockIdx.x * 256 + tid] = 0;

    if (blockIdx.x < Hdim) {
        // ---------------- Wcomb fold ----------------
        float* sWo = (float*)smem;
        const int o = blockIdx.x;
        const int j = tid;
        sWo[j] = W_oI[o * Hdim + j];
        __syncthreads();
        float a0 = 0.f, a1 = 0.f, a2 = 0.f, a3 = 0.f;
        #pragma unroll 8
        for (int i = 0; i < Hdim; i += 4) {
            a0 += sWo[i + 0] * W_Ih[(i + 0) * Hdim + j];
            a1 += sWo[i + 1] * W_Ih[(i + 1) * Hdim + j];
            a2 += sWo[i + 2] * W_Ih[(i + 2) * Hdim + j];
            a3 += sWo[i + 3] * W_Ih[(i + 3) * Hdim + j];
        }
        const float acc = (a0 + a1) + (a2 + a3);
        const int dst = (o >> 4) * 4096 + (j >> 5) * 512 + ((j >> 3) & 3) * 128
                      + (o & 15) * 8 + (j & 7);
        Wph[dst] = f2h_rne(acc);
        float pT = sWo[j] * W_I1T[j];
        float pL = sWo[j] * W_I1L[j];
        #pragma unroll
        for (int d = 1; d < 64; d <<= 1) {
            pT += __shfl_xor(pT, d, 64);
            pL += __shfl_xor(pL, d, 64);
        }
        if (lane == 0) { redT[w] = pT; redL[w] = pL; }
        __syncthreads();
        if (j == 0) {
            wT2[o] = redT[0] + redT[1] + redT[2] + redT[3];
            wL2[o] = redL[0] + redL[1] + redL[2] + redL[3];
        }
    } else {
        // ---------------- cp2 MFMA: 16 batches per block ----------------
        char* hh_b  = smem;                // [16][512] fp16 swizzled (16 KB)
        char* cpl_b = smem + 16384;        // [16][256] fp16 swizzled (8 KB)
        const int b0 = (blockIdx.x - Hdim) * 16;
        const u32 swzA = (u32)((c & 7) << 4);
        const f32x4 fz = {0.f, 0.f, 0.f, 0.f};

        // stage h_hat rows b0..b0+15 -> fp16 swizzled (row stride 1024 B)
        {
            const int srow = tid >> 4;     // 16 threads per row
            const int sj = tid & 15;       // 32 floats each
            const u32 sbb = (u32)(srow * 1024);
            const u32 ssz = (u32)((srow & 7) << 4);
            #pragma unroll
            for (int ch = 0; ch < 2; ++ch) {
                const int col = sj * 32 + ch * 16;
                const float* src = (col < Hdim)
                    ? (h_tilde + (size_t)(b0 + srow) * Hdim + col)
                    : (c_t + (size_t)(b0 + srow) * Hdim + col - Hdim);
                float4 f0 = *(const float4*)(src + 0);
                float4 f1 = *(const float4*)(src + 4);
                float4 f2 = *(const float4*)(src + 8);
                float4 f3 = *(const float4*)(src + 12);
                uint4 ua = make_uint4(cvt_pk_f16(f0.x, f0.y), cvt_pk_f16(f0.z, f0.w),
                                      cvt_pk_f16(f1.x, f1.y), cvt_pk_f16(f1.z, f1.w));
                uint4 ub = make_uint4(cvt_pk_f16(f2.x, f2.y), cvt_pk_f16(f2.z, f2.w),
                                      cvt_pk_f16(f3.x, f3.y), cvt_pk_f16(f3.z, f3.w));
                *(uint4*)(hh_b + ((sbb + (u32)(col * 2) + 0) ^ ssz)) = ua;
                *(uint4*)(hh_b + ((sbb + (u32)(col * 2) + 16) ^ ssz)) = ub;
            }
        }
        __syncthreads();

        // GEMM1: cpl = h_hat @ W_I^T + b_I (K=512; rows 0..15 -> single m-frag)
        f32x4 acc[4];
        #pragma unroll
        for (int n = 0; n < 4; ++n) acc[n] = fz;
        #pragma unroll
        for (int ks = 0; ks < 16; ++ks) {
            const s16x8 a = *(const s16x8*)(hh_b +
                (((u32)(c * 1024 + ks * 64 + g * 16)) ^ swzA));
            #pragma unroll
            for (int n = 0; n < 4; ++n) {
                const int o = w * 64 + n * 16 + c;
                const s16x8 bf = bfrag_f32(W_I + (size_t)o * (2 * Hdim) + ks * 32 + g * 8);
                acc[n] = mfma16h(a, bf, acc[n]);
            }
        }
        // epilogue 1: +b_I, pair-pack fp16 -> cpl (row stride 512 B)
        #pragma unroll
        for (int n = 0; n < 4; ++n) {
            const int o = w * 64 + n * 16 + c;
            const float bi = b_I[o];
            const u32 ocol2 = (u32)((o & ~1) * 2);
            #pragma unroll
            for (int r = 0; r < 4; ++r) {
                const int row = g * 4 + r;
                float z = acc[n][r] + bi;
                float zsw = __shfl_xor(z, 1, 64);
                if (!(c & 1)) {
                    u32 h2 = cvt_pk_f16(z, zsw);
                    *(u32*)(cpl_b + (((u32)(row * 512) + ocol2) ^ ((u32)((row & 7) << 4)))) = h2;
                }
            }
        }
        __syncthreads();

        // GEMM2: cp2 = cpl @ W_oI^T + b_oI (K=256)
        f32x4 acc2[4];
        #pragma unroll
        for (int n = 0; n < 4; ++n) acc2[n] = fz;
        #pragma unroll
        for (int ks = 0; ks < 8; ++ks) {
            const s16x8 a = *(const s16x8*)(cpl_b +
                (((u32)(c * 512 + ks * 64 + g * 16)) ^ swzA));
            #pragma unroll
            for (int n = 0; n < 4; ++n) {
                const int o = w * 64 + n * 16 + c;
                const s16x8 bf = bfrag_f32(W_oI + (size_t)o * Hdim + ks * 32 + g * 8);
                acc2[n] = mfma16h(a, bf, acc2[n]);
            }
        }
        #pragma unroll
        for (int n = 0; n < 4; ++n) {
            const int o = w * 64 + n * 16 + c;
            const float bo = b_oI[o];
            #pragma unroll
            for (int r = 0; r < 4; ++r)
                cp2[(size_t)(b0 + g * 4 + r) * Hdim + o] = acc2[n][r] + bo;
        }
    }
}

// ---- pass 1: fp16 GEMM -> scores + tile partials; LAST tile-block combines -----
// (r19 body; adds atomic-counter tail replacing the separate combine kernel.)
__global__ __launch_bounds__(NTHR, 4) void scores_kernel(
        const float* __restrict__ hist, const float* __restrict__ dT,
        const float* __restrict__ dL, const float* __restrict__ cp2,
        const u16* __restrict__ Wph,
        const float* __restrict__ wT2, const float* __restrict__ wL2,
        const float* __restrict__ v_t, float* __restrict__ out,
        float* __restrict__ Spart, float* __restrict__ mpart,
        float* __restrict__ lpart, int* __restrict__ cnt) {
    __shared__ u16 lds_u[TT * Hdim];           // 32 KB hist tile (fp16, swizzled)
    __shared__ float dtl[TT], dll[TT];
    __shared__ float sc_part[4][TT];
    __shared__ float p_sh[TT];
    __shared__ float ml_sh[2];
    __shared__ float sacc2[2][Hdim];
    __shared__ int amlast;
    __shared__ float fsh2[4], invl_sh, msh;

    float* scores = out + Bdim * Hdim;
    const int bid = blockIdx.x;
    const int b = bid >> 2;                    // NTILE = 4
    const int t0 = (bid & 3) * TT;
    const int tid = threadIdx.x;
    const int w = tid >> 6, lane = tid & 63;
    const int c = lane & 15, g = lane >> 4;
    const int ob = w * 64;

    const int wfrag = lane * 8;
    #define WOFF(n, ks) ((w * 4 + (n)) * 4096 + (ks) * 512 + wfrag)

    if (tid < TT) {
        dtl[tid] = dT[b * Tdim + t0 + tid];
        dll[tid] = dL[b * Tdim + t0 + tid];
    }

    // ---- stage hist tile: 64 rows x 256 cols fp32 -> fp16 swizzled --------------
    {
        const int srow = tid >> 2;
        const int sj = tid & 3;
        const float* srcb = hist + ((size_t)b * Tdim + t0 + srow) * Hdim;
        const u32 sbb = (u32)(srow * 512);
        const u32 ssz = (u32)((srow & 7) << 4);
        char* dst = (char*)lds_u;
        #pragma unroll
        for (int ch = 0; ch < 4; ++ch) {
            const int col = ch * 64 + sj * 16;
            float4 f0 = *(const float4*)(srcb + col + 0);
            float4 f1 = *(const float4*)(srcb + col + 4);
            float4 f2 = *(const float4*)(srcb + col + 8);
            float4 f3 = *(const float4*)(srcb + col + 12);
            uint4 ua = make_uint4(cvt_pk_f16(f0.x, f0.y), cvt_pk_f16(f0.z, f0.w),
                                  cvt_pk_f16(f1.x, f1.y), cvt_pk_f16(f1.z, f1.w));
            uint4 ub = make_uint4(cvt_pk_f16(f2.x, f2.y), cvt_pk_f16(f2.z, f2.w),
                                  cvt_pk_f16(f3.x, f3.y), cvt_pk_f16(f3.z, f3.w));
            *(uint4*)(dst + ((sbb + (u32)(col * 2) + 0) ^ ssz)) = ua;
            *(uint4*)(dst + ((sbb + (u32)(col * 2) + 16) ^ ssz)) = ub;
        }
    }
    __syncthreads();

    const f32x4 fz = {0.f, 0.f, 0.f, 0.f};
    const u32 swzA = (u32)((c & 7) << 4);

    // ================= GEMM: z = hist @ Wcomb^T, fp16 (direct B loads) ==========
    f32x4 acc[4][4];
    #pragma unroll
    for (int m = 0; m < 4; ++m)
        #pragma unroll
        for (int n = 0; n < 4; ++n) acc[m][n] = fz;
    {
        const char* hb = (const char*)lds_u;
        #pragma unroll
        for (int ks = 0; ks < 8; ++ks) {
            s16x8 a[4];
            #pragma unroll
            for (int m = 0; m < 4; ++m)
                a[m] = *(const s16x8*)(hb +
                    (((u32)((m * 16 + c) * 512 + g * 16 + ks * 64)) ^ swzA));
            #pragma unroll
            for (int n = 0; n < 4; ++n) {
                const s16x8 bh = *(const s16x8*)(Wph + WOFF(n, ks));
                #pragma unroll
                for (int m = 0; m < 4; ++m)
                    acc[m][n] = mfma16h(a[m], bh, acc[m][n]);
            }
        }
    }

    // ---- epilogue: tanh, dot v, 16-lane reduce ----------------------------------
    float cpv[4], wtv[4], wlv[4], vvv[4];
    #pragma unroll
    for (int n = 0; n < 4; ++n) {
        const int o = ob + n * 16 + c;
        cpv[n] = cp2[(size_t)b * Hdim + o];
        wtv[n] = wT2[o];
        wlv[n] = wL2[o];
        vvv[n] = v_t[o];
    }
    #pragma unroll
    for (int m = 0; m < 4; ++m) {
        #pragma unroll
        for (int r = 0; r < 4; ++r) {
            const int row = m * 16 + g * 4 + r;
            const float dtr = dtl[row], dlr = dll[row];
            float s = 0.f;
            #pragma unroll
            for (int n = 0; n < 4; ++n) {
                float z = acc[m][n][r] + cpv[n] + dtr * wtv[n] + dlr * wlv[n];
                s += fast_tanh(z) * vvv[n];
            }
            s += __shfl_xor(s, 1, 64);
            s += __shfl_xor(s, 2, 64);
            s += __shfl_xor(s, 4, 64);
            s += __shfl_xor(s, 8, 64);
            if (c == 0) sc_part[w][row] = s;
        }
    }
    __syncthreads();

    // ---- tile softmax partials (wave 0) -----------------------------------------
    if (tid < TT) {
        float s = sc_part[0][tid] + sc_part[1][tid] + sc_part[2][tid] + sc_part[3][tid];
        scores[b * Tdim + t0 + tid] = s;
        float mx = s;
        #pragma unroll
        for (int d = 1; d < 64; d <<= 1) mx = fmaxf(mx, __shfl_xor(mx, d, 64));
        float p = __expf(s - mx);
        float l = p;
        #pragma unroll
        for (int d = 1; d < 64; d <<= 1) l += __shfl_xor(l, d, 64);
        p_sh[tid] = p;
        if (tid == 0) { ml_sh[0] = mx; ml_sh[1] = l; }
    }
    __syncthreads();

    // ---- S_k[o] = sum_t p_t * hist[t,o]  (from staged fp16 LDS tile) ------------
    {
        const int half = tid >> 7;
        const int pp = tid & 127;
        const char* hb = (const char*)lds_u;
        float s0 = 0.f, s1 = 0.f;
        #pragma unroll 8
        for (int i = 0; i < 32; ++i) {
            const int t = half * 32 + i;
            const float pv = p_sh[t];
            const u32 hw = *(const u32*)(hb + (((u32)(t * 512 + pp * 4)) ^ ((u32)((t & 7) << 4))));
            const f16x2 hv = __builtin_bit_cast(f16x2, hw);
            s0 += pv * (float)hv[0];
            s1 += pv * (float)hv[1];
        }
        sacc2[half][2 * pp] = s0;
        sacc2[half][2 * pp + 1] = s1;
    }
    __syncthreads();
    Spart[(size_t)bid * Hdim + tid] = sacc2[0][tid] + sacc2[1][tid];
    if (tid == 0) { mpart[bid] = ml_sh[0]; lpart[bid] = ml_sh[1]; }

    // ---- last tile-block of this batch combines (replaces combine kernel) -------
    __threadfence();   // release: Spart/mpart/lpart + raw scores visible
    if (tid == 0) amlast = (atomicAdd(&cnt[b], 1) == NTILE - 1) ? 1 : 0;
    __syncthreads();
    if (amlast) {
        __threadfence();   // acquire
        if (tid == 0) {
            const float m0 = mpart[4 * b + 0], m1 = mpart[4 * b + 1];
            const float m2 = mpart[4 * b + 2], m3 = mpart[4 * b + 3];
            const float m = fmaxf(fmaxf(m0, m1), fmaxf(m2, m3));
            const float f0 = __expf(m0 - m), f1 = __expf(m1 - m);
            const float f2 = __expf(m2 - m), f3 = __expf(m3 - m);
            const float l = f0 * lpart[4 * b + 0] + f1 * lpart[4 * b + 1]
                          + f2 * lpart[4 * b + 2] + f3 * lpart[4 * b + 3];
            fsh2[0] = f0; fsh2[1] = f1; fsh2[2] = f2; fsh2[3] = f3;
            invl_sh = 1.0f / l;
            msh = m;
        }
        __syncthreads();
        const float inv_l = invl_sh;
        const float S = fsh2[0] * Spart[(size_t)(4 * b + 0) * Hdim + tid]
                      + fsh2[1] * Spart[(size_t)(4 * b + 1) * Hdim + tid]
                      + fsh2[2] * Spart[(size_t)(4 * b + 2) * Hdim + tid]
                      + fsh2[3] * Spart[(size_t)(4 * b + 3) * Hdim + tid];
        out[b * Hdim + tid] = S * inv_l;
        const float sc = scores[b * Tdim + tid];
        scores[b * Tdim + tid] = __expf(sc - msh) * inv_l;
    }
    #undef WOFF
}

extern "C" void kernel_launch(void* const* d_in, const int* in_sizes, int n_in,
                              void* d_out, int out_size, void* d_ws, size_t ws_size,
                              hipStream_t stream) {
    const float* h_tilde = (const float*)d_in[0];
    const float* c_t     = (const float*)d_in[1];
    const float* hist    = (const float*)d_in[2];
    const float* dT      = (const float*)d_in[3];
    const float* dL      = (const float*)d_in[4];
    const float* W_I     = (const float*)d_in[5];
    const float* W_Ih    = (const float*)d_in[6];
    const float* W_I1T   = (const float*)d_in[7];
    const float* W_I1L   = (const float*)d_in[8];
    const float* b_I     = (const float*)d_in[9];
    const float* W_oI    = (const float*)d_in[10];
    const float* b_oI    = (const float*)d_in[11];
    const float* v_t     = (const float*)d_in[12];
    float* out = (float*)d_out;

    char* ws = (char*)d_ws;
    u16* Wph     = (u16*)ws;                          // 128 KB (fp16)
    float* cp2   = (float*)(ws + 131072);             // 512 KB
    float* wT2   = (float*)(ws + 655360);             // 1 KB
    float* wL2   = (float*)(ws + 656384);             // 1 KB
    float* Spart = (float*)(ws + 657408);             // 2 MB
    float* mpart = (float*)(ws + 657408 + 2097152);   // 8 KB
    float* lpart = (float*)(ws + 657408 + 2105344);   // 8 KB
    int*   cnt   = (int*)(ws + 657408 + 2113536);     // 2 KB (512 counters)

    prep_kernel<<<dim3(Hdim + NCP), dim3(256), 0, stream>>>(
        W_Ih, W_oI, W_I1T, W_I1L, h_tilde, c_t, W_I, b_I, b_oI,
        Wph, wT2, wL2, cp2, cnt);
    scores_kernel<<<dim3(Bdim * NTILE), dim3(NTHR), 0, stream>>>(
        hist, dT, dL, cp2, Wph, wT2, wL2, v_t, out, Spart, mpart, lpart, cnt);
}

// Round 21
// 80.532 us; speedup vs baseline: 4.1808x; 4.1808x over previous
//
#include <hip/hip_runtime.h>
#include <hip/hip_bf16.h>
#include <hip/hip_fp16.h>

#define Hdim 256
#define Tdim 256
#define Bdim 512
#define TT   64
#define NTILE (Tdim / TT)   // 4
#define NTHR 256
#define NCP  32             // cp2 prep blocks (16 batches each)

typedef __attribute__((ext_vector_type(8))) short s16x8;
typedef __attribute__((ext_vector_type(8))) _Float16 f16x8;
typedef __attribute__((ext_vector_type(2))) _Float16 f16x2;
typedef __attribute__((ext_vector_type(4))) float f32x4;
typedef unsigned short u16;
typedef unsigned int u32;

__device__ __forceinline__ u32 cvt_pk_f16(float lo, float hi) {
    auto v = __builtin_amdgcn_cvt_pkrtz(lo, hi);
    return __builtin_bit_cast(u32, v);
}
__device__ __forceinline__ u16 f2h_rne(float x) {
    _Float16 h = (_Float16)x;
    return __builtin_bit_cast(u16, h);
}
__device__ __forceinline__ f32x4 mfma16h(s16x8 a, s16x8 b, f32x4 c) {
    return __builtin_amdgcn_mfma_f32_16x16x32_f16(
        __builtin_bit_cast(f16x8, a), __builtin_bit_cast(f16x8, b), c, 0, 0, 0);
}
__device__ __forceinline__ float fast_tanh(float z) {
    float e = __expf(2.0f * z);
    return 1.0f - 2.0f * __builtin_amdgcn_rcpf(e + 1.0f);
}
__device__ __forceinline__ s16x8 bfrag_f32(const float* __restrict__ wp) {
    float4 x0 = *(const float4*)(wp + 0);
    float4 x1 = *(const float4*)(wp + 4);
    uint4 uu = make_uint4(cvt_pk_f16(x0.x, x0.y), cvt_pk_f16(x0.z, x0.w),
                          cvt_pk_f16(x1.x, x1.y), cvt_pk_f16(x1.z, x1.w));
    return __builtin_bit_cast(s16x8, uu);
}

// ---- prep: [0,256) Wcomb fold; [256,256+NCP) cp2 MFMA, 16 batches per block ----
// (r20's 32-way cp2 parallelism, WITHOUT r20's fence/atomic combine machinery.)
__global__ __launch_bounds__(256) void prep_kernel(
        const float* __restrict__ W_Ih, const float* __restrict__ W_oI,
        const float* __restrict__ W_I1T, const float* __restrict__ W_I1L,
        const float* __restrict__ h_tilde, const float* __restrict__ c_t,
        const float* __restrict__ W_I, const float* __restrict__ b_I,
        const float* __restrict__ b_oI,
        u16* __restrict__ Wph, float* __restrict__ wT2, float* __restrict__ wL2,
        float* __restrict__ cp2) {
    __shared__ char smem[24576];           // fold: sWo 1KB | cp2: hh 16KB + cpl 8KB
    __shared__ float redT[4], redL[4];
    const int tid = threadIdx.x;
    const int w = tid >> 6, lane = tid & 63;
    const int c = lane & 15, g = lane >> 4;

    if (blockIdx.x < Hdim) {
        // ---------------- Wcomb fold ----------------
        float* sWo = (float*)smem;
        const int o = blockIdx.x;
        const int j = tid;
        sWo[j] = W_oI[o * Hdim + j];
        __syncthreads();
        float a0 = 0.f, a1 = 0.f, a2 = 0.f, a3 = 0.f;
        #pragma unroll 8
        for (int i = 0; i < Hdim; i += 4) {
            a0 += sWo[i + 0] * W_Ih[(i + 0) * Hdim + j];
            a1 += sWo[i + 1] * W_Ih[(i + 1) * Hdim + j];
            a2 += sWo[i + 2] * W_Ih[(i + 2) * Hdim + j];
            a3 += sWo[i + 3] * W_Ih[(i + 3) * Hdim + j];
        }
        const float acc = (a0 + a1) + (a2 + a3);
        const int dst = (o >> 4) * 4096 + (j >> 5) * 512 + ((j >> 3) & 3) * 128
                      + (o & 15) * 8 + (j & 7);
        Wph[dst] = f2h_rne(acc);
        float pT = sWo[j] * W_I1T[j];
        float pL = sWo[j] * W_I1L[j];
        #pragma unroll
        for (int d = 1; d < 64; d <<= 1) {
            pT += __shfl_xor(pT, d, 64);
            pL += __shfl_xor(pL, d, 64);
        }
        if (lane == 0) { redT[w] = pT; redL[w] = pL; }
        __syncthreads();
        if (j == 0) {
            wT2[o] = redT[0] + redT[1] + redT[2] + redT[3];
            wL2[o] = redL[0] + redL[1] + redL[2] + redL[3];
        }
    } else {
        // ---------------- cp2 MFMA: 16 batches per block ----------------
        char* hh_b  = smem;                // [16][512] fp16 swizzled (16 KB)
        char* cpl_b = smem + 16384;        // [16][256] fp16 swizzled (8 KB)
        const int b0 = (blockIdx.x - Hdim) * 16;
        const u32 swzA = (u32)((c & 7) << 4);
        const f32x4 fz = {0.f, 0.f, 0.f, 0.f};

        // stage h_hat rows b0..b0+15 -> fp16 swizzled (row stride 1024 B)
        {
            const int srow = tid >> 4;     // 16 threads per row
            const int sj = tid & 15;       // 32 floats each
            const u32 sbb = (u32)(srow * 1024);
            const u32 ssz = (u32)((srow & 7) << 4);
            #pragma unroll
            for (int ch = 0; ch < 2; ++ch) {
                const int col = sj * 32 + ch * 16;
                const float* src = (col < Hdim)
                    ? (h_tilde + (size_t)(b0 + srow) * Hdim + col)
                    : (c_t + (size_t)(b0 + srow) * Hdim + col - Hdim);
                float4 f0 = *(const float4*)(src + 0);
                float4 f1 = *(const float4*)(src + 4);
                float4 f2 = *(const float4*)(src + 8);
                float4 f3 = *(const float4*)(src + 12);
                uint4 ua = make_uint4(cvt_pk_f16(f0.x, f0.y), cvt_pk_f16(f0.z, f0.w),
                                      cvt_pk_f16(f1.x, f1.y), cvt_pk_f16(f1.z, f1.w));
                uint4 ub = make_uint4(cvt_pk_f16(f2.x, f2.y), cvt_pk_f16(f2.z, f2.w),
                                      cvt_pk_f16(f3.x, f3.y), cvt_pk_f16(f3.z, f3.w));
                *(uint4*)(hh_b + ((sbb + (u32)(col * 2) + 0) ^ ssz)) = ua;
                *(uint4*)(hh_b + ((sbb + (u32)(col * 2) + 16) ^ ssz)) = ub;
            }
        }
        __syncthreads();

        // GEMM1: cpl = h_hat @ W_I^T + b_I (K=512; rows 0..15 -> single m-frag)
        f32x4 acc[4];
        #pragma unroll
        for (int n = 0; n < 4; ++n) acc[n] = fz;
        #pragma unroll
        for (int ks = 0; ks < 16; ++ks) {
            const s16x8 a = *(const s16x8*)(hh_b +
                (((u32)(c * 1024 + ks * 64 + g * 16)) ^ swzA));
            #pragma unroll
            for (int n = 0; n < 4; ++n) {
                const int o = w * 64 + n * 16 + c;
                const s16x8 bf = bfrag_f32(W_I + (size_t)o * (2 * Hdim) + ks * 32 + g * 8);
                acc[n] = mfma16h(a, bf, acc[n]);
            }
        }
        // epilogue 1: +b_I, pair-pack fp16 -> cpl (row stride 512 B)
        #pragma unroll
        for (int n = 0; n < 4; ++n) {
            const int o = w * 64 + n * 16 + c;
            const float bi = b_I[o];
            const u32 ocol2 = (u32)((o & ~1) * 2);
            #pragma unroll
            for (int r = 0; r < 4; ++r) {
                const int row = g * 4 + r;
                float z = acc[n][r] + bi;
                float zsw = __shfl_xor(z, 1, 64);
                if (!(c & 1)) {
                    u32 h2 = cvt_pk_f16(z, zsw);
                    *(u32*)(cpl_b + (((u32)(row * 512) + ocol2) ^ ((u32)((row & 7) << 4)))) = h2;
                }
            }
        }
        __syncthreads();

        // GEMM2: cp2 = cpl @ W_oI^T + b_oI (K=256)
        f32x4 acc2[4];
        #pragma unroll
        for (int n = 0; n < 4; ++n) acc2[n] = fz;
        #pragma unroll
        for (int ks = 0; ks < 8; ++ks) {
            const s16x8 a = *(const s16x8*)(cpl_b +
                (((u32)(c * 512 + ks * 64 + g * 16)) ^ swzA));
            #pragma unroll
            for (int n = 0; n < 4; ++n) {
                const int o = w * 64 + n * 16 + c;
                const s16x8 bf = bfrag_f32(W_oI + (size_t)o * Hdim + ks * 32 + g * 8);
                acc2[n] = mfma16h(a, bf, acc2[n]);
            }
        }
        #pragma unroll
        for (int n = 0; n < 4; ++n) {
            const int o = w * 64 + n * 16 + c;
            const float bo = b_oI[o];
            #pragma unroll
            for (int r = 0; r < 4; ++r)
                cp2[(size_t)(b0 + g * 4 + r) * Hdim + o] = acc2[n][r] + bo;
        }
    }
}

// ---- pass 1 (r19-verified): fp16 GEMM -> scores + tile softmax partials --------
__global__ __launch_bounds__(NTHR, 4) void scores_kernel(
        const float* __restrict__ hist, const float* __restrict__ dT,
        const float* __restrict__ dL, const float* __restrict__ cp2,
        const u16* __restrict__ Wph,
        const float* __restrict__ wT2, const float* __restrict__ wL2,
        const float* __restrict__ v_t, float* __restrict__ scores,
        float* __restrict__ Spart, float* __restrict__ mpart,
        float* __restrict__ lpart) {
    __shared__ u16 lds_u[TT * Hdim];           // 32 KB hist tile (fp16, swizzled)
    __shared__ float dtl[TT], dll[TT];
    __shared__ float sc_part[4][TT];
    __shared__ float p_sh[TT];
    __shared__ float ml_sh[2];
    __shared__ float sacc2[2][Hdim];

    const int bid = blockIdx.x;
    const int b = bid >> 2;                    // NTILE = 4
    const int t0 = (bid & 3) * TT;
    const int tid = threadIdx.x;
    const int w = tid >> 6, lane = tid & 63;
    const int c = lane & 15, g = lane >> 4;
    const int ob = w * 64;

    const int wfrag = lane * 8;
    #define WOFF(n, ks) ((w * 4 + (n)) * 4096 + (ks) * 512 + wfrag)

    if (tid < TT) {
        dtl[tid] = dT[b * Tdim + t0 + tid];
        dll[tid] = dL[b * Tdim + t0 + tid];
    }

    // ---- stage hist tile: 64 rows x 256 cols fp32 -> fp16 swizzled --------------
    {
        const int srow = tid >> 2;
        const int sj = tid & 3;
        const float* srcb = hist + ((size_t)b * Tdim + t0 + srow) * Hdim;
        const u32 sbb = (u32)(srow * 512);
        const u32 ssz = (u32)((srow & 7) << 4);
        char* dst = (char*)lds_u;
        #pragma unroll
        for (int ch = 0; ch < 4; ++ch) {
            const int col = ch * 64 + sj * 16;
            float4 f0 = *(const float4*)(srcb + col + 0);
            float4 f1 = *(const float4*)(srcb + col + 4);
            float4 f2 = *(const float4*)(srcb + col + 8);
            float4 f3 = *(const float4*)(srcb + col + 12);
            uint4 ua = make_uint4(cvt_pk_f16(f0.x, f0.y), cvt_pk_f16(f0.z, f0.w),
                                  cvt_pk_f16(f1.x, f1.y), cvt_pk_f16(f1.z, f1.w));
            uint4 ub = make_uint4(cvt_pk_f16(f2.x, f2.y), cvt_pk_f16(f2.z, f2.w),
                                  cvt_pk_f16(f3.x, f3.y), cvt_pk_f16(f3.z, f3.w));
            *(uint4*)(dst + ((sbb + (u32)(col * 2) + 0) ^ ssz)) = ua;
            *(uint4*)(dst + ((sbb + (u32)(col * 2) + 16) ^ ssz)) = ub;
        }
    }
    __syncthreads();

    const f32x4 fz = {0.f, 0.f, 0.f, 0.f};
    const u32 swzA = (u32)((c & 7) << 4);

    // ================= GEMM: z = hist @ Wcomb^T, fp16 (direct B loads) ==========
    f32x4 acc[4][4];
    #pragma unroll
    for (int m = 0; m < 4; ++m)
        #pragma unroll
        for (int n = 0; n < 4; ++n) acc[m][n] = fz;
    {
        const char* hb = (const char*)lds_u;
        #pragma unroll
        for (int ks = 0; ks < 8; ++ks) {
            s16x8 a[4];
            #pragma unroll
            for (int m = 0; m < 4; ++m)
                a[m] = *(const s16x8*)(hb +
                    (((u32)((m * 16 + c) * 512 + g * 16 + ks * 64)) ^ swzA));
            #pragma unroll
            for (int n = 0; n < 4; ++n) {
                const s16x8 bh = *(const s16x8*)(Wph + WOFF(n, ks));
                #pragma unroll
                for (int m = 0; m < 4; ++m)
                    acc[m][n] = mfma16h(a[m], bh, acc[m][n]);
            }
        }
    }

    // ---- epilogue consts loaded AFTER GEMM (keeps GEMM-live regs minimal) -------
    float cpv[4], wtv[4], wlv[4], vvv[4];
    #pragma unroll
    for (int n = 0; n < 4; ++n) {
        const int o = ob + n * 16 + c;
        cpv[n] = cp2[(size_t)b * Hdim + o];
        wtv[n] = wT2[o];
        wlv[n] = wL2[o];
        vvv[n] = v_t[o];
    }
    #pragma unroll
    for (int m = 0; m < 4; ++m) {
        #pragma unroll
        for (int r = 0; r < 4; ++r) {
            const int row = m * 16 + g * 4 + r;
            const float dtr = dtl[row], dlr = dll[row];
            float s = 0.f;
            #pragma unroll
            for (int n = 0; n < 4; ++n) {
                float z = acc[m][n][r] + cpv[n] + dtr * wtv[n] + dlr * wlv[n];
                s += fast_tanh(z) * vvv[n];
            }
            s += __shfl_xor(s, 1, 64);
            s += __shfl_xor(s, 2, 64);
            s += __shfl_xor(s, 4, 64);
            s += __shfl_xor(s, 8, 64);
            if (c == 0) sc_part[w][row] = s;
        }
    }
    __syncthreads();

    // ---- tile softmax partials (wave 0) -----------------------------------------
    if (tid < TT) {
        float s = sc_part[0][tid] + sc_part[1][tid] + sc_part[2][tid] + sc_part[3][tid];
        scores[b * Tdim + t0 + tid] = s;
        float mx = s;
        #pragma unroll
        for (int d = 1; d < 64; d <<= 1) mx = fmaxf(mx, __shfl_xor(mx, d, 64));
        float p = __expf(s - mx);
        float l = p;
        #pragma unroll
        for (int d = 1; d < 64; d <<= 1) l += __shfl_xor(l, d, 64);
        p_sh[tid] = p;
        if (tid == 0) { ml_sh[0] = mx; ml_sh[1] = l; }
    }
    __syncthreads();

    // ---- S_k[o] = sum_t p_t * hist[t,o]  (from staged fp16 LDS tile) ------------
    {
        const int half = tid >> 7;
        const int pp = tid & 127;
        const char* hb = (const char*)lds_u;
        float s0 = 0.f, s1 = 0.f;
        #pragma unroll 8
        for (int i = 0; i < 32; ++i) {
            const int t = half * 32 + i;
            const float pv = p_sh[t];
            const u32 hw = *(const u32*)(hb + (((u32)(t * 512 + pp * 4)) ^ ((u32)((t & 7) << 4))));
            const f16x2 hv = __builtin_bit_cast(f16x2, hw);
            s0 += pv * (float)hv[0];
            s1 += pv * (float)hv[1];
        }
        sacc2[half][2 * pp] = s0;
        sacc2[half][2 * pp + 1] = s1;
    }
    __syncthreads();
    Spart[(size_t)bid * Hdim + tid] = sacc2[0][tid] + sacc2[1][tid];
    if (tid == 0) { mpart[bid] = ml_sh[0]; lpart[bid] = ml_sh[1]; }
    #undef WOFF
}

// ---- pass 2: combine 4 tile-partials per batch -> s_t and alpha -----------------
__global__ __launch_bounds__(256) void combine_kernel(
        const float* __restrict__ Spart, const float* __restrict__ mpart,
        const float* __restrict__ lpart, float* __restrict__ out) {
    const int b = blockIdx.x;
    const int tid = threadIdx.x;
    __shared__ float fsh[4], inv_l_sh, m_sh;
    if (tid == 0) {
        const float m0 = mpart[4 * b + 0], m1 = mpart[4 * b + 1];
        const float m2 = mpart[4 * b + 2], m3 = mpart[4 * b + 3];
        const float m = fmaxf(fmaxf(m0, m1), fmaxf(m2, m3));
        const float f0 = __expf(m0 - m), f1 = __expf(m1 - m);
        const float f2 = __expf(m2 - m), f3 = __expf(m3 - m);
        const float l = f0 * lpart[4 * b + 0] + f1 * lpart[4 * b + 1]
                      + f2 * lpart[4 * b + 2] + f3 * lpart[4 * b + 3];
        fsh[0] = f0; fsh[1] = f1; fsh[2] = f2; fsh[3] = f3;
        inv_l_sh = 1.0f / l;
        m_sh = m;
    }
    __syncthreads();
    const float inv_l = inv_l_sh;
    const float S = fsh[0] * Spart[(size_t)(4 * b + 0) * Hdim + tid]
                  + fsh[1] * Spart[(size_t)(4 * b + 1) * Hdim + tid]
                  + fsh[2] * Spart[(size_t)(4 * b + 2) * Hdim + tid]
                  + fsh[3] * Spart[(size_t)(4 * b + 3) * Hdim + tid];
    out[b * Hdim + tid] = S * inv_l;
    float* scores = out + Bdim * Hdim;
    const float sc = scores[b * Tdim + tid];
    scores[b * Tdim + tid] = __expf(sc - m_sh) * inv_l;
}

extern "C" void kernel_launch(void* const* d_in, const int* in_sizes, int n_in,
                              void* d_out, int out_size, void* d_ws, size_t ws_size,
                              hipStream_t stream) {
    const float* h_tilde = (const float*)d_in[0];
    const float* c_t     = (const float*)d_in[1];
    const float* hist    = (const float*)d_in[2];
    const float* dT      = (const float*)d_in[3];
    const float* dL      = (const float*)d_in[4];
    const float* W_I     = (const float*)d_in[5];
    const float* W_Ih    = (const float*)d_in[6];
    const float* W_I1T   = (const float*)d_in[7];
    const float* W_I1L   = (const float*)d_in[8];
    const float* b_I     = (const float*)d_in[9];
    const float* W_oI    = (const float*)d_in[10];
    const float* b_oI    = (const float*)d_in[11];
    const float* v_t     = (const float*)d_in[12];
    float* out = (float*)d_out;

    char* ws = (char*)d_ws;
    u16* Wph     = (u16*)ws;                          // 128 KB (fp16)
    float* cp2   = (float*)(ws + 131072);             // 512 KB
    float* wT2   = (float*)(ws + 655360);             // 1 KB
    float* wL2   = (float*)(ws + 656384);             // 1 KB
    float* Spart = (float*)(ws + 657408);             // 2 MB
    float* mpart = (float*)(ws + 657408 + 2097152);   // 8 KB
    float* lpart = (float*)(ws + 657408 + 2105344);   // 8 KB
    float* scores = out + Bdim * Hdim;                // raw scores into alpha slot

    prep_kernel<<<dim3(Hdim + NCP), dim3(256), 0, stream>>>(
        W_Ih, W_oI, W_I1T, W_I1L, h_tilde, c_t, W_I, b_I, b_oI,
        Wph, wT2, wL2, cp2);
    scores_kernel<<<dim3(Bdim * NTILE), dim3(NTHR), 0, stream>>>(
        hist, dT, dL, cp2, Wph, wT2, wL2, v_t, scores, Spart, mpart, lpart);
    combine_kernel<<<dim3(Bdim), dim3(256), 0, stream>>>(Spart, mpart, lpart, out);
}